// Round 8
// baseline (103.599 us; speedup 1.0000x reference)
//
#include <hip/hip_runtime.h>
#include <stdint.h>

typedef float f32x4 __attribute__((ext_vector_type(4)));
typedef int   i32x4 __attribute__((ext_vector_type(4)));
typedef __bf16 bf16x8 __attribute__((ext_vector_type(8)));

#define NN 8192
#define DDIM 128
#define RSTRIDE 144   // LDS tile row: 64 bf16 (128 B) + 16 B pad

// LDS byte offsets (single-buffered split tiles, BK=64)
#define OFF_AH 0
#define OFF_AL 18432
#define OFF_BH 36864
#define OFF_BL 55296
#define OFF_ILS 73728
#define OFF_N1  74240
#define OFF_N2  74752
#define LDS_TOT 75264

__device__ __forceinline__ uint32_t pk2(__bf16 a, __bf16 b) {
    return (uint32_t)__builtin_bit_cast(unsigned short, a)
         | ((uint32_t)__builtin_bit_cast(unsigned short, b) << 16);
}

// RNE hi/lo split of 4 scaled f32 (round-3/5/6/7-verified numerics)
__device__ __forceinline__ void split4(f32x4 x, uint2& hi, uint2& lo) {
    __bf16 h0 = (__bf16)x[0], h1 = (__bf16)x[1], h2 = (__bf16)x[2], h3 = (__bf16)x[3];
    hi.x = pk2(h0, h1); hi.y = pk2(h2, h3);
    __bf16 l0 = (__bf16)(x[0] - (float)h0);
    __bf16 l1 = (__bf16)(x[1] - (float)h1);
    __bf16 l2 = (__bf16)(x[2] - (float)h2);
    __bf16 l3 = (__bf16)(x[3] - (float)h3);
    lo.x = pk2(l0, l1); lo.y = pk2(l2, l3);
}

// Barrier that does NOT drain vmcnt: LDS-visibility only, order-pinned
// (rule #18: sched_barrier around so nothing is hoisted across). Verified R7.
__device__ __forceinline__ void lds_barrier() {
    asm volatile("s_waitcnt lgkmcnt(0)" ::: "memory");
    __builtin_amdgcn_sched_barrier(0);
    __builtin_amdgcn_s_barrier();
    __builtin_amdgcn_sched_barrier(0);
}

// Fused TGP: split-once-to-LDS bf16 3-term GEMM + in-LDS norms + fused epilogue.
// 128x128 tile, 512 threads = 8 waves (2 row-halves x 4 col-quarters, 64x32 each).
// BK=64 (2 chunks), single-buffered tiles, 5 barriers total, 2 blocks/CU.
__global__ __launch_bounds__(512, 4) void tgp_kernel(
    const float* __restrict__ X1, const float* __restrict__ X2,
    const float* __restrict__ log_l,
    const float* __restrict__ log_theta_l, const float* __restrict__ bparam,
    const int* __restrict__ task1, const int* __restrict__ task2,
    float* __restrict__ C)
{
    __shared__ __align__(16) char smem[LDS_TOT];
    float* const ils = (float*)(smem + OFF_ILS);
    float* const n1s = (float*)(smem + OFF_N1);
    float* const n2s = (float*)(smem + OFF_N2);

    const int t = threadIdx.x;            // 0..511
    const int lane = t & 63;
    const int wv = t >> 6;                // 0..7
    const int wr = wv >> 2, wc = wv & 3;  // 2 x 4 wave grid, 64x32 tiles
    const int lr = lane & 15, lg = lane >> 4;
    const int kq = t & 15;                // f32x4 col-group within 64-col chunk
    const int rg = t >> 4;                // 0..31 row within each 32-row stripe

    // L2 super-tile ordering (verified R7): XCD x owns A-row band x and
    // sweeps B in 8-tile super-columns. Bijective for nwg=4096.
    int wg = blockIdx.x;
    int xcd = wg & 7;
    int r = wg >> 3;
    int su = r >> 6;
    int inner = r & 63;
    int tm = xcd * 8 + (inner >> 3);
    int tn = su * 8 + (inner & 7);

    const float* Ag = X1 + (size_t)tm * 128 * DDIM;
    const float* Bg = X2 + (size_t)tn * 128 * DDIM;

    if (t < 128) ils[t] = __expf(-log_l[t]);
    __syncthreads();   // ils visible

    float nA[4] = {0.f, 0.f, 0.f, 0.f};
    float nB[4] = {0.f, 0.f, 0.f, 0.f};
    f32x4 acc[4][2];
    #pragma unroll
    for (int i = 0; i < 4; ++i)
        #pragma unroll
        for (int j = 0; j < 2; ++j) acc[i][j] = (f32x4){0.f, 0.f, 0.f, 0.f};

    #pragma unroll
    for (int c = 0; c < 2; ++c) {
        // ---- P1: coalesced load (16 f32/thread/side), scale, norm, split, write ----
        {
            f32x4 il4 = *(const f32x4*)(ils + c * 64 + kq * 4);
            #pragma unroll
            for (int e = 0; e < 4; ++e) {
                int row = e * 32 + rg;
                f32x4 xa = *(const f32x4*)(Ag + (size_t)row * DDIM + c * 64 + kq * 4);
                f32x4 xb = *(const f32x4*)(Bg + (size_t)row * DDIM + c * 64 + kq * 4);
                xa *= il4; xb *= il4;
                nA[e] += xa[0]*xa[0] + xa[1]*xa[1] + xa[2]*xa[2] + xa[3]*xa[3];
                nB[e] += xb[0]*xb[0] + xb[1]*xb[1] + xb[2]*xb[2] + xb[3]*xb[3];
                uint2 hA, lA, hB, lB;
                split4(xa, hA, lA);
                split4(xb, hB, lB);
                int boff = row * RSTRIDE + kq * 8;
                *(uint2*)(smem + OFF_AH + boff) = hA;
                *(uint2*)(smem + OFF_AL + boff) = lA;
                *(uint2*)(smem + OFF_BH + boff) = hB;
                *(uint2*)(smem + OFF_BL + boff) = lB;
            }
        }
        lds_barrier();   // split tiles visible

        // ---- P2: frag reads + MFMA, 2 K-steps of 32, term-ordered for low VGPR ----
        #pragma unroll
        for (int ks = 0; ks < 2; ++ks) {
            int kb = ks * 64;   // byte offset of K-step within tile row
            bf16x8 ah[4], bx[2], xf[4];
            #pragma unroll
            for (int mi = 0; mi < 4; ++mi) {
                int off = (wr * 64 + mi * 16 + lr) * RSTRIDE + kb + lg * 16;
                ah[mi] = *(const bf16x8*)(smem + OFF_AH + off);
            }
            #pragma unroll
            for (int ni = 0; ni < 2; ++ni) {
                int off = (wc * 32 + ni * 16 + lr) * RSTRIDE + kb + lg * 16;
                bx[ni] = *(const bf16x8*)(smem + OFF_BH + off);
            }
            #pragma unroll
            for (int mi = 0; mi < 4; ++mi)
                #pragma unroll
                for (int ni = 0; ni < 2; ++ni)
                    acc[mi][ni] = __builtin_amdgcn_mfma_f32_16x16x32_bf16(bx[ni], ah[mi], acc[mi][ni], 0, 0, 0);
            // al x bh
            #pragma unroll
            for (int mi = 0; mi < 4; ++mi) {
                int off = (wr * 64 + mi * 16 + lr) * RSTRIDE + kb + lg * 16;
                xf[mi] = *(const bf16x8*)(smem + OFF_AL + off);
            }
            #pragma unroll
            for (int mi = 0; mi < 4; ++mi)
                #pragma unroll
                for (int ni = 0; ni < 2; ++ni)
                    acc[mi][ni] = __builtin_amdgcn_mfma_f32_16x16x32_bf16(bx[ni], xf[mi], acc[mi][ni], 0, 0, 0);
            // ah x bl
            #pragma unroll
            for (int ni = 0; ni < 2; ++ni) {
                int off = (wc * 32 + ni * 16 + lr) * RSTRIDE + kb + lg * 16;
                bx[ni] = *(const bf16x8*)(smem + OFF_BL + off);
            }
            #pragma unroll
            for (int mi = 0; mi < 4; ++mi)
                #pragma unroll
                for (int ni = 0; ni < 2; ++ni)
                    acc[mi][ni] = __builtin_amdgcn_mfma_f32_16x16x32_bf16(bx[ni], ah[mi], acc[mi][ni], 0, 0, 0);
        }
        if (c == 0) lds_barrier();   // reads done before chunk 1 overwrites
    }

    // ---- norm reduce over kq (lane bits 0..3); lane kq==0 owns row rg ----
    #pragma unroll
    for (int e = 0; e < 4; ++e) {
        #pragma unroll
        for (int off = 1; off < 16; off <<= 1) {
            nA[e] += __shfl_xor(nA[e], off);
            nB[e] += __shfl_xor(nB[e], off);
        }
    }
    if (kq == 0) {
        #pragma unroll
        for (int e = 0; e < 4; ++e) {
            n1s[e * 32 + rg] = nA[e];
            n2s[e * 32 + rg] = nB[e];
        }
    }
    __syncthreads();   // norms visible

    // ---- epilogue (verified mapping): lane lr = A-row slice,
    //      reg r = 4 consecutive cols at lg*4 (swapped operands) ----
    float logt = log_theta_l[0];
    float bb = bparam[0];
    float lam = fminf(fmaxf(2.f / (1.f + __expf(bb)) - 1.f, 0.f), 1.f);
    int rbase = tm * 128, cbase = tn * 128;

    #pragma unroll
    for (int mi = 0; mi < 4; ++mi) {
        int rowl = wr * 64 + mi * 16 + lr;
        float n1v = n1s[rowl];
        int t1v = task1[rbase + rowl];
        #pragma unroll
        for (int ni = 0; ni < 2; ++ni) {
            int coll = wc * 32 + ni * 16 + lg * 4;
            f32x4 n2v = *(const f32x4*)(n2s + coll);
            i32x4 t2v = *(const i32x4*)(task2 + cbase + coll);
            f32x4 kv;
            #pragma unroll
            for (int rix = 0; rix < 4; ++rix) {
                float s = fmaxf(n1v + n2v[rix] - 2.f * acc[mi][ni][rix], 0.f);
                float k = __expf(fmaf(-0.5f, s, logt));
                kv[rix] = (t1v != t2v[rix]) ? k * lam : k;
            }
            *(f32x4*)(C + (size_t)(rbase + rowl) * NN + cbase + coll) = kv;
        }
    }
}

extern "C" void kernel_launch(void* const* d_in, const int* in_sizes, int n_in,
                              void* d_out, int out_size, void* d_ws, size_t ws_size,
                              hipStream_t stream)
{
    const float* X1 = (const float*)d_in[0];
    const float* X2 = (const float*)d_in[1];
    const float* log_l = (const float*)d_in[2];
    const float* log_theta = (const float*)d_in[3];
    const float* bp = (const float*)d_in[4];
    const int* t1 = (const int*)d_in[5];
    const int* t2 = (const int*)d_in[6];
    float* C = (float*)d_out;
    (void)d_ws; (void)ws_size; (void)in_sizes; (void)n_in; (void)out_size;

    tgp_kernel<<<4096, 512, 0, stream>>>(X1, X2, log_l, log_theta, bp, t1, t2, C);
}